// Round 3
// baseline (580.234 us; speedup 1.0000x reference)
//
#include <hip/hip_runtime.h>

#define LBL 64
#define SEQN 512
#define BATCHN 512
#define START_ID 62
#define PAD_ID 63
#define CH 8            // steps per chunk; renorm at tt==0 (every 8th step)

typedef float v2f __attribute__((ext_vector_type(2)));
typedef float v4f __attribute__((ext_vector_type(4)));

// 256 blocks x 64 threads (1 wave). Each wave advances TWO chains (b, b+256),
// staggered so one chain's LDS latency hides under the other's FMAs.
// Linear-space recurrence A <- (A . expT) * exp(e); broadcast via uniform-addr
// ds_read_b128; renorm every 8 steps via exact 2^k scale from exponent field.
__global__ __launch_bounds__(64) void crf_batch_kernel(
    const float* __restrict__ ts,      // [B,S,L]
    const float* __restrict__ T,       // [L,L]
    const int*   __restrict__ labels,  // [B,S]
    const int*   __restrict__ lengths, // [B]
    float*       __restrict__ ws)      // [B] out: fwd_b - gold_b
{
  const int b0 = blockIdx.x;
  const int b1 = b0 + (BATCHN / 2);
  const int j = threadIdx.x;  // 0..63

  __shared__ __align__(16) float buf0[LBL];
  __shared__ __align__(16) float buf1[LBL];

  const int len0 = lengths[b0];
  const int len1 = lengths[b1];
  const float* __restrict__ e0 = ts + (size_t)b0 * SEQN * LBL;
  const float* __restrict__ e1 = ts + (size_t)b1 * SEQN * LBL;
  const int* __restrict__ lab0 = labels + b0 * SEQN;
  const int* __restrict__ lab1 = labels + b1 * SEQN;

  // expT column j as 32 packed pairs: c2[m] = {exp(T[2m][j]), exp(T[2m+1][j])}
  v2f c2[32];
#pragma unroll
  for (int m = 0; m < 32; ++m) {
    c2[m].x = __expf(T[(2 * m) * LBL + j]);
    c2[m].y = __expf(T[(2 * m + 1) * LBL + j]);
  }
  const float expPad = __expf(T[j * LBL + PAD_ID]);

  // emission double-buffers (all statically indexed)
  float eC0[CH], eN0[CH], eC1[CH], eN1[CH];
#pragma unroll
  for (int r = 0; r < CH; ++r) { eC0[r] = e0[r * LBL + j]; eC1[r] = e1[r * LBL + j]; }
#pragma unroll
  for (int r = 0; r < CH; ++r) { eN0[r] = e0[(CH + r) * LBL + j]; eN1[r] = e1[(CH + r) * LBL + j]; }

  float A0 = __expf(eC0[0] + T[START_ID * LBL + j]);
  float A1 = __expf(eC1[0] + T[START_ID * LBL + j]);
  int E0 = 0, E1 = 0;  // stored = true * 2^E

  buf0[j] = A0;
  buf1[j] = A1;

  const int lenmax = (len0 > len1) ? len0 : len1;

  for (int t0 = 0; t0 < lenmax; t0 += CH) {
#pragma unroll
    for (int tt = 0; tt < CH; ++tt) {
      const int t = t0 + tt;
      const bool renorm = (tt == 0);  // static: t0 is a multiple of 8
      const bool act0 = (t >= 1) && (t < len0);
      const bool act1 = (t >= 1) && (t < len1);

      // ---- chain 0: read broadcast quads, packed FMA ----
      v2f a00 = {0.f, 0.f}, a01 = {0.f, 0.f}, a02 = {0.f, 0.f}, a03 = {0.f, 0.f};
      v2f mx0 = {0.f, 0.f};
#pragma unroll
      for (int k = 0; k < 16; ++k) {
        const v4f q = *(const v4f*)(buf0 + 4 * k);  // uniform addr -> broadcast
        const v2f qlo = __builtin_shufflevector(q, q, 0, 1);
        const v2f qhi = __builtin_shufflevector(q, q, 2, 3);
        if ((k & 3) == 0) { a00 = __builtin_elementwise_fma(qlo, c2[2 * k], a00);
                            a01 = __builtin_elementwise_fma(qhi, c2[2 * k + 1], a01); }
        else if ((k & 3) == 1) { a02 = __builtin_elementwise_fma(qlo, c2[2 * k], a02);
                            a03 = __builtin_elementwise_fma(qhi, c2[2 * k + 1], a03); }
        else if ((k & 3) == 2) { a00 = __builtin_elementwise_fma(qlo, c2[2 * k], a00);
                            a01 = __builtin_elementwise_fma(qhi, c2[2 * k + 1], a01); }
        else { a02 = __builtin_elementwise_fma(qlo, c2[2 * k], a02);
               a03 = __builtin_elementwise_fma(qhi, c2[2 * k + 1], a03); }
        if (renorm) {
          mx0 = __builtin_elementwise_max(mx0, __builtin_elementwise_max(qlo, qhi));
        }
      }
      {
        const v2f s2 = (a00 + a01) + (a02 + a03);
        const float sum = s2.x + s2.y;
        float ex = __expf(eC0[tt]);
        int dE = 0;
        if (renorm) {
          const float m = fmaxf(mx0.x, mx0.y);
          const unsigned em = (__float_as_uint(m) >> 23) & 0xffu;
          ex *= __uint_as_float((254u - em) << 23);  // * 2^(127-em), exact
          dE = 127 - (int)em;
        }
        const float nA = sum * ex;
        A0 = act0 ? nA : A0;
        if (renorm) E0 += act0 ? dE : 0;
        buf0[j] = A0;  // in-order LDS: reads above already issued; next step sees this
      }

      // ---- chain 1 (staggered: its reads/FMAs cover chain0's write latency) ----
      v2f a10 = {0.f, 0.f}, a11 = {0.f, 0.f}, a12 = {0.f, 0.f}, a13 = {0.f, 0.f};
      v2f mx1 = {0.f, 0.f};
#pragma unroll
      for (int k = 0; k < 16; ++k) {
        const v4f q = *(const v4f*)(buf1 + 4 * k);
        const v2f qlo = __builtin_shufflevector(q, q, 0, 1);
        const v2f qhi = __builtin_shufflevector(q, q, 2, 3);
        if ((k & 3) == 0) { a10 = __builtin_elementwise_fma(qlo, c2[2 * k], a10);
                            a11 = __builtin_elementwise_fma(qhi, c2[2 * k + 1], a11); }
        else if ((k & 3) == 1) { a12 = __builtin_elementwise_fma(qlo, c2[2 * k], a12);
                            a13 = __builtin_elementwise_fma(qhi, c2[2 * k + 1], a13); }
        else if ((k & 3) == 2) { a10 = __builtin_elementwise_fma(qlo, c2[2 * k], a10);
                            a11 = __builtin_elementwise_fma(qhi, c2[2 * k + 1], a11); }
        else { a12 = __builtin_elementwise_fma(qlo, c2[2 * k], a12);
               a13 = __builtin_elementwise_fma(qhi, c2[2 * k + 1], a13); }
        if (renorm) {
          mx1 = __builtin_elementwise_max(mx1, __builtin_elementwise_max(qlo, qhi));
        }
      }
      {
        const v2f s2 = (a10 + a11) + (a12 + a13);
        const float sum = s2.x + s2.y;
        float ex = __expf(eC1[tt]);
        int dE = 0;
        if (renorm) {
          const float m = fmaxf(mx1.x, mx1.y);
          const unsigned em = (__float_as_uint(m) >> 23) & 0xffu;
          ex *= __uint_as_float((254u - em) << 23);
          dE = 127 - (int)em;
        }
        const float nA = sum * ex;
        A1 = act1 ? nA : A1;
        if (renorm) E1 += act1 ? dE : 0;
        buf1[j] = A1;
      }
    }

    // rotate emission buffers; prefetch chunk t0/CH + 2 (consumed 8-16 steps later)
#pragma unroll
    for (int r = 0; r < CH; ++r) { eC0[r] = eN0[r]; eC1[r] = eN1[r]; }
    const int tb = (t0 + 2 * CH <= SEQN - CH) ? (t0 + 2 * CH) : (SEQN - CH);
#pragma unroll
    for (int r = 0; r < CH; ++r) { eN0[r] = e0[(tb + r) * LBL + j]; eN1[r] = e1[(tb + r) * LBL + j]; }
  }

  // ---- gold path scores (lane-strided over t) ----
  float g0 = 0.0f, g1 = 0.0f;
  for (int t = j; t < len0; t += 64) {
    const int l = lab0[t];
    const int prev = (t == 0) ? START_ID : lab0[t - 1];
    g0 += T[prev * LBL + l] + e0[t * LBL + l];
  }
  for (int t = j; t < len1; t += 64) {
    const int l = lab1[t];
    const int prev = (t == 0) ? START_ID : lab1[t - 1];
    g1 += T[prev * LBL + l] + e1[t * LBL + l];
  }

  // ---- final logsumexp + wave reductions ----
  float v0 = A0 * expPad;
  float v1 = A1 * expPad;
#pragma unroll
  for (int d = 1; d < 64; d <<= 1) {
    v0 += __shfl_xor(v0, d);
    g0 += __shfl_xor(g0, d);
    v1 += __shfl_xor(v1, d);
    g1 += __shfl_xor(g1, d);
  }

  if (j == 0) {
    const float ln2 = 0.69314718055994531f;
    const float gold0 = g0 + T[lab0[len0 - 1] * LBL + PAD_ID];
    const float gold1 = g1 + T[lab1[len1 - 1] * LBL + PAD_ID];
    ws[b0] = (logf(v0) - (float)E0 * ln2) - gold0;
    ws[b1] = (logf(v1) - (float)E1 * ln2) - gold1;
  }
}

__global__ __launch_bounds__(256) void crf_reduce_kernel(
    const float* __restrict__ ws, float* __restrict__ out)
{
  __shared__ float red[4];
  const int tid = threadIdx.x;  // 256 threads
  float v = ws[tid] + ws[tid + 256];
#pragma unroll
  for (int d = 1; d < 64; d <<= 1) v += __shfl_xor(v, d);
  if ((tid & 63) == 0) red[tid >> 6] = v;
  __syncthreads();
  if (tid == 0) out[0] = (red[0] + red[1] + red[2] + red[3]) * (1.0f / BATCHN);
}

extern "C" void kernel_launch(void* const* d_in, const int* in_sizes, int n_in,
                              void* d_out, int out_size, void* d_ws, size_t ws_size,
                              hipStream_t stream) {
  const float* ts      = (const float*)d_in[0];
  const float* T       = (const float*)d_in[1];
  const int*   labels  = (const int*)d_in[2];
  const int*   lengths = (const int*)d_in[3];
  float* out = (float*)d_out;
  float* ws  = (float*)d_ws;

  crf_batch_kernel<<<BATCHN / 2, 64, 0, stream>>>(ts, T, labels, lengths, ws);
  crf_reduce_kernel<<<1, 256, 0, stream>>>(ws, out);
}

// Round 6
// 244.635 us; speedup vs baseline: 2.3718x; 2.3718x over previous
//
#include <hip/hip_runtime.h>

#define LBL 64
#define SEQN 512
#define BATCHN 512
#define START_ID 62
#define PAD_ID 63
#define CH 8            // steps per chunk; renorm at tt==0 (every 8th step)

// One block per batch element, 64 threads = 1 wave. Lane j owns label-state j.
// Linear-space recurrence A <- (A . expT) * exp(e).
// Broadcast of A[i] to all lanes via ds_swizzle(and=0,or=k): lane k -> lanes
// 0-31 of each 32-half simultaneously (2 broadcasts per DS op), plus one
// ds_bpermute half-swap for the other half's values. DS pipe overlaps VALU
// FMAs. Renorm every 8 steps: VALU fmax tree over the (wave-uniform)
// broadcast values; exact power-of-2 rescale via exponent-field arithmetic.
__global__ __launch_bounds__(64) void crf_batch_kernel(
    const float* __restrict__ ts,      // [B,S,L]
    const float* __restrict__ T,       // [L,L]
    const int*   __restrict__ labels,  // [B,S]
    const int*   __restrict__ lengths, // [B]
    float*       __restrict__ ws)      // [B] out: fwd_b - gold_b
{
  const int b = blockIdx.x;
  const int j = threadIdx.x;  // 0..63
  const int len = lengths[b];
  const float* __restrict__ e_b = ts + (size_t)b * SEQN * LBL;
  const int* __restrict__ lab_b = labels + b * SEQN;

  const int half = j & 32;
  // Phase-1 swizzle k delivers A[k+half'] where half' = lane's own half.
  // So lane j must multiply by expT[k + half][j]; phase 2 (after half-swap)
  // delivers A[k + (half^32)] -> coefficient expT[k + (half^32)][j].
  float c1[32], c2[32];
#pragma unroll
  for (int k = 0; k < 32; ++k) {
    c1[k] = __expf(T[(k + half) * LBL + j]);
    c2[k] = __expf(T[(k + (half ^ 32)) * LBL + j]);
  }
  const float expPad = __expf(T[j * LBL + PAD_ID]);  // exp(T[j, PAD])
  const int swap_addr = (j ^ 32) << 2;               // ds_bpermute byte index

  // Emission buffers: raw loads (latency hidden over 8 steps), exp at rotate.
  float eC[CH], eNraw[CH];
#pragma unroll
  for (int r = 0; r < CH; ++r) eC[r] = __expf(e_b[r * LBL + j]);
#pragma unroll
  for (int r = 0; r < CH; ++r) eNraw[r] = e_b[(CH + r) * LBL + j];

  float A = __expf(e_b[j] + T[START_ID * LBL + j]);  // alpha0, linear space
  int E = 0;  // stored = true * 2^E (exact power-of-2 bookkeeping)

  for (int t0 = 0; t0 < len; t0 += CH) {
#pragma unroll
    for (int tt = 0; tt < CH; ++tt) {
      const int t = t0 + tt;
      if (t >= 1 && t < len) {   // wave-uniform branch
        const int Ab = __float_as_int(A);
        const int A2b = __builtin_amdgcn_ds_bpermute(swap_addr, Ab);

        // All 64 broadcasts issued up front -> DS pipe fills, granular lgkm.
        // ds_swizzle offset must be a LITERAL -> macro-expand all 32 pairs.
        float bc[64];
#define SWZ_PAIR(K)                                                            \
        bc[K]      = __int_as_float(__builtin_amdgcn_ds_swizzle(Ab,  (K) << 5)); \
        bc[32+(K)] = __int_as_float(__builtin_amdgcn_ds_swizzle(A2b, (K) << 5));
        SWZ_PAIR(0)  SWZ_PAIR(1)  SWZ_PAIR(2)  SWZ_PAIR(3)
        SWZ_PAIR(4)  SWZ_PAIR(5)  SWZ_PAIR(6)  SWZ_PAIR(7)
        SWZ_PAIR(8)  SWZ_PAIR(9)  SWZ_PAIR(10) SWZ_PAIR(11)
        SWZ_PAIR(12) SWZ_PAIR(13) SWZ_PAIR(14) SWZ_PAIR(15)
        SWZ_PAIR(16) SWZ_PAIR(17) SWZ_PAIR(18) SWZ_PAIR(19)
        SWZ_PAIR(20) SWZ_PAIR(21) SWZ_PAIR(22) SWZ_PAIR(23)
        SWZ_PAIR(24) SWZ_PAIR(25) SWZ_PAIR(26) SWZ_PAIR(27)
        SWZ_PAIR(28) SWZ_PAIR(29) SWZ_PAIR(30) SWZ_PAIR(31)
#undef SWZ_PAIR

        float s[4] = {0.f, 0.f, 0.f, 0.f};
#pragma unroll
        for (int k = 0; k < 32; ++k)
          s[k & 3] = fmaf(bc[k], c1[k], s[k & 3]);
#pragma unroll
        for (int k = 0; k < 32; ++k)
          s[k & 3] = fmaf(bc[32 + k], c2[k], s[k & 3]);

        float ex = eC[tt];
        if (tt == 0) {  // renorm: first step of each chunk (t = 8, 16, ...)
          float m[32];
#pragma unroll
          for (int k = 0; k < 32; ++k) m[k] = fmaxf(bc[k], bc[32 + k]);
#pragma unroll
          for (int st = 16; st >= 1; st >>= 1)
#pragma unroll
            for (int k = 0; k < 16; ++k)
              if (k < st) m[k] = fmaxf(m[k], m[k + st]);
          const unsigned em = (__float_as_uint(m[0]) >> 23) & 255u;
          ex *= __uint_as_float((254u - em) << 23);  // * 2^(127-em), exact
          E += 127 - (int)em;
        }
        A = ((s[0] + s[1]) + (s[2] + s[3])) * ex;
      }
    }

    // rotate (exp now: loads are 8 steps old -> latency hidden) + prefetch
#pragma unroll
    for (int r = 0; r < CH; ++r) eC[r] = __expf(eNraw[r]);
    const int tb = (t0 + 2 * CH <= SEQN - CH) ? (t0 + 2 * CH) : (SEQN - CH);
#pragma unroll
    for (int r = 0; r < CH; ++r) eNraw[r] = e_b[(tb + r) * LBL + j];
  }

  // ---- gold path score (lane-strided over t) ----
  float g = 0.0f;
  for (int t = j; t < len; t += 64) {
    const int l = lab_b[t];
    const int prev = (t == 0) ? START_ID : lab_b[t - 1];
    g += T[prev * LBL + l] + e_b[t * LBL + l];
  }

  // ---- final logsumexp + wave reductions ----
  float v = A * expPad;
#pragma unroll
  for (int d = 1; d < 64; d <<= 1) {
    v += __shfl_xor(v, d);
    g += __shfl_xor(g, d);
  }

  if (j == 0) {
    const int last = lab_b[len - 1];
    const float gold = g + T[last * LBL + PAD_ID];
    const float fwd = logf(v) - (float)E * 0.69314718055994531f;
    ws[b] = fwd - gold;
  }
}

__global__ __launch_bounds__(256) void crf_reduce_kernel(
    const float* __restrict__ ws, float* __restrict__ out)
{
  __shared__ float red[4];
  const int tid = threadIdx.x;  // 256 threads
  float v = ws[tid] + ws[tid + 256];
#pragma unroll
  for (int d = 1; d < 64; d <<= 1) v += __shfl_xor(v, d);
  if ((tid & 63) == 0) red[tid >> 6] = v;
  __syncthreads();
  if (tid == 0) out[0] = (red[0] + red[1] + red[2] + red[3]) * (1.0f / BATCHN);
}

extern "C" void kernel_launch(void* const* d_in, const int* in_sizes, int n_in,
                              void* d_out, int out_size, void* d_ws, size_t ws_size,
                              hipStream_t stream) {
  const float* ts      = (const float*)d_in[0];
  const float* T       = (const float*)d_in[1];
  const int*   labels  = (const int*)d_in[2];
  const int*   lengths = (const int*)d_in[3];
  float* out = (float*)d_out;
  float* ws  = (float*)d_ws;

  crf_batch_kernel<<<BATCHN, 64, 0, stream>>>(ts, T, labels, lengths, ws);
  crf_reduce_kernel<<<1, 256, 0, stream>>>(ws, out);
}

// Round 7
// 214.877 us; speedup vs baseline: 2.7003x; 1.1385x over previous
//
#include <hip/hip_runtime.h>

#define LBL 64
#define SEQN 512
#define BATCHN 512
#define START_ID 62
#define PAD_ID 63
#define CH 8            // steps per chunk; renorm at tt==0 (every 8th step)

// One block per batch element, 64 threads = 1 wave. Lane j owns label-state j.
// Linear-space recurrence A <- (A . expT) * exp(e).
// Broadcast: phase 1 issues 64 v_readlane into a 64-SGPR block, then a
// sched_barrier(0) fence, then phase 2's 64 FMAs read each SGPR >=64
// instructions after its write (no VALU->SGPR->VALU wait states).
// Renorm every 8 steps via SALU umax tree over the SGPR block (A>0 so
// uint-compare works) -- runs on the scalar pipe, off the critical path.
__global__ __launch_bounds__(64) void crf_batch_kernel(
    const float* __restrict__ ts,      // [B,S,L]
    const float* __restrict__ T,       // [L,L]
    const int*   __restrict__ labels,  // [B,S]
    const int*   __restrict__ lengths, // [B]
    float*       __restrict__ ws)      // [B] out: fwd_b - gold_b
{
  const int b = blockIdx.x;
  const int j = threadIdx.x;  // 0..63
  const int len = lengths[b];
  const float* __restrict__ e_b = ts + (size_t)b * SEQN * LBL;
  const int* __restrict__ lab_b = labels + b * SEQN;

  // expT column j in registers: c[i] = exp(T[i][j]). Coalesced loads.
  float c[LBL];
#pragma unroll
  for (int i = 0; i < LBL; ++i) c[i] = __expf(T[i * LBL + j]);
  const float expPad = __expf(T[j * LBL + PAD_ID]);  // exp(T[j, PAD])

  // Emission buffers: raw loads (latency hidden over 8 steps), exp at rotate.
  float eC[CH], eNraw[CH];
#pragma unroll
  for (int r = 0; r < CH; ++r) eC[r] = __expf(e_b[r * LBL + j]);
#pragma unroll
  for (int r = 0; r < CH; ++r) eNraw[r] = e_b[(CH + r) * LBL + j];

  float A = __expf(e_b[j] + T[START_ID * LBL + j]);  // alpha0, linear space
  int E = 0;  // stored = true * 2^E (exact power-of-2 bookkeeping)

  for (int t0 = 0; t0 < len; t0 += CH) {
#pragma unroll
    for (int tt = 0; tt < CH; ++tt) {
      const int t = t0 + tt;
      if (t >= 1 && t < len) {   // wave-uniform branch
        const int Ab = __float_as_int(A);

        // ---- phase 1: all 64 readlanes -> SGPR block ----
        int sg[LBL];
#pragma unroll
        for (int k = 0; k < LBL; ++k) sg[k] = __builtin_amdgcn_readlane(Ab, k);

        __builtin_amdgcn_sched_barrier(0);  // pin two-phase structure

        // ---- phase 2: 64 FMAs, SGPR broadcast operand ----
        float s0 = 0.f, s1 = 0.f, s2 = 0.f, s3 = 0.f;
#pragma unroll
        for (int k = 0; k < LBL; k += 4) {
          s0 = fmaf(__int_as_float(sg[k + 0]), c[k + 0], s0);
          s1 = fmaf(__int_as_float(sg[k + 1]), c[k + 1], s1);
          s2 = fmaf(__int_as_float(sg[k + 2]), c[k + 2], s2);
          s3 = fmaf(__int_as_float(sg[k + 3]), c[k + 3], s3);
        }

        float ex = eC[tt];
        if (tt == 0) {  // renorm: SALU umax tree (parallel with VALU FMAs)
          unsigned m[32];
#pragma unroll
          for (int k = 0; k < 32; ++k) {
            const unsigned a = (unsigned)sg[k], bu = (unsigned)sg[k + 32];
            m[k] = a > bu ? a : bu;
          }
#pragma unroll
          for (int st = 16; st >= 1; st >>= 1)
#pragma unroll
            for (int k = 0; k < 16; ++k)
              if (k < st) m[k] = m[k] > m[k + st] ? m[k] : m[k + st];
          const unsigned em = (m[0] >> 23) & 255u;
          ex *= __uint_as_float((254u - em) << 23);  // * 2^(127-em), exact
          E += 127 - (int)em;
        }
        A = ((s0 + s1) + (s2 + s3)) * ex;
      }
    }

    // rotate (exp now: loads are 8 steps old -> latency hidden) + prefetch
#pragma unroll
    for (int r = 0; r < CH; ++r) eC[r] = __expf(eNraw[r]);
    const int tb = (t0 + 2 * CH <= SEQN - CH) ? (t0 + 2 * CH) : (SEQN - CH);
#pragma unroll
    for (int r = 0; r < CH; ++r) eNraw[r] = e_b[(tb + r) * LBL + j];
  }

  // ---- gold path score (lane-strided over t) ----
  float g = 0.0f;
  for (int t = j; t < len; t += 64) {
    const int l = lab_b[t];
    const int prev = (t == 0) ? START_ID : lab_b[t - 1];
    g += T[prev * LBL + l] + e_b[t * LBL + l];
  }

  // ---- final logsumexp + wave reductions ----
  float v = A * expPad;
#pragma unroll
  for (int d = 1; d < 64; d <<= 1) {
    v += __shfl_xor(v, d);
    g += __shfl_xor(g, d);
  }

  if (j == 0) {
    const int last = lab_b[len - 1];
    const float gold = g + T[last * LBL + PAD_ID];
    const float fwd = logf(v) - (float)E * 0.69314718055994531f;
    ws[b] = fwd - gold;
  }
}

__global__ __launch_bounds__(256) void crf_reduce_kernel(
    const float* __restrict__ ws, float* __restrict__ out)
{
  __shared__ float red[4];
  const int tid = threadIdx.x;  // 256 threads
  float v = ws[tid] + ws[tid + 256];
#pragma unroll
  for (int d = 1; d < 64; d <<= 1) v += __shfl_xor(v, d);
  if ((tid & 63) == 0) red[tid >> 6] = v;
  __syncthreads();
  if (tid == 0) out[0] = (red[0] + red[1] + red[2] + red[3]) * (1.0f / BATCHN);
}

extern "C" void kernel_launch(void* const* d_in, const int* in_sizes, int n_in,
                              void* d_out, int out_size, void* d_ws, size_t ws_size,
                              hipStream_t stream) {
  const float* ts      = (const float*)d_in[0];
  const float* T       = (const float*)d_in[1];
  const int*   labels  = (const int*)d_in[2];
  const int*   lengths = (const int*)d_in[3];
  float* out = (float*)d_out;
  float* ws  = (float*)d_ws;

  crf_batch_kernel<<<BATCHN, 64, 0, stream>>>(ts, T, labels, lengths, ws);
  crf_reduce_kernel<<<1, 256, 0, stream>>>(ws, out);
}